// Round 3
// baseline (2149.169 us; speedup 1.0000x reference)
//
#include <hip/hip_runtime.h>
#include <math.h>

#define BATCH 128
#define SLEN  8000
#define HID   64
#define CHUNK 64                  // steps per fc flush; 8000 = 125 * 64
#define NCHUNK (SLEN / CHUNK)     // 125
#define ROWSTRIDE 68              // floats; 272 B rows, 16B-aligned

typedef float v2f __attribute__((ext_vector_type(2)));

__device__ __forceinline__ float fast_exp2(float x) { return __builtin_amdgcn_exp2f(x); }
__device__ __forceinline__ float fast_rcp(float x)  { return __builtin_amdgcn_rcpf(x); }

__device__ __forceinline__ float bcast_lane(float v, int lane) {
    return __int_as_float(__builtin_amdgcn_readlane(__float_as_int(v), lane));
}

// tanh(x) = sign(x) * (e - 1)/(e + 1), e = 2^(2|x|*log2 e)
__device__ __forceinline__ float tanh_fast(float x) {
    float ax = fabsf(x);
    float z  = fminf(ax * 2.8853900817779268f, 30.0f);
    float e  = fast_exp2(z);
    float r  = (e - 1.0f) * fast_rcp(e + 1.0f);
    return x < 0.0f ? -r : r;
}

__device__ __forceinline__ float sigmoid_fast(float x) {
    float z = fminf(fmaxf(-x * 1.4426950408889634f, -60.0f), 60.0f);
    float e = fast_exp2(z);
    return fast_rcp(1.0f + e);
}

__global__ __launch_bounds__(64) void rnn_pk_kernel(
    const float* __restrict__ x,      // [B, S]
    const float* __restrict__ W_ih,   // [H, 1]
    const float* __restrict__ b_ih,   // [H]
    const float* __restrict__ W_hh,   // [H, H]
    const float* __restrict__ b_hh,   // [H]
    const float* __restrict__ fc_w,   // [2, H]
    const float* __restrict__ fc_b,   // [2]
    float* __restrict__ out)          // [B]
{
    __shared__ float hbuf[CHUNK * ROWSTRIDE];   // h history; also the broadcast medium

    const int lane = threadIdx.x;               // == hidden index i
    const int b    = blockIdx.x;
    const float* xrow = x + (size_t)b * SLEN;

    // Lane i holds W_hh row i as 32 packed float2 (64 VGPRs)
    v2f W2[32];
    #pragma unroll
    for (int q = 0; q < 16; ++q) {
        float4 t = ((const float4*)(W_hh + lane * HID))[q];
        W2[2*q+0] = (v2f){t.x, t.y};
        W2[2*q+1] = (v2f){t.z, t.w};
    }
    const float wih  = W_ih[lane];
    const float bias = b_ih[lane] + b_hh[lane];
    const float fcb0 = fc_b[0], fcb1 = fc_b[1];

    float h = 0.0f;                 // distributed: lane i holds h[i]
    float num = 0.0f, den = 0.0f;

    float xv_next = xrow[lane];     // chunk 0's x (one value per lane)

    #pragma unroll 1
    for (int c = 0; c < NCHUNK; ++c) {
        float xcur = xv_next;
        int nidx = (c + 1 < NCHUNK) ? (c + 1) * CHUNK + lane : lane;
        xv_next = xrow[nidx];       // prefetch next chunk's x (off critical path)

        #pragma unroll 2
        for (int r = 0; r < CHUNK; ++r) {
            // broadcast x_t — depends only on xcur, issues early
            float xv = bcast_lane(xcur, r);

            // publish h_t: single wave, DS pipe is in-order -> no barrier
            hbuf[r * ROWSTRIDE + lane] = h;

            // all-gather h_t via same-address broadcast b128 reads (conflict-free)
            const float4* rowp = (const float4*)(hbuf + r * ROWSTRIDE);
            v2f acc0 = (v2f){fmaf(wih, xv, bias), 0.0f};
            v2f acc1 = (v2f){0.0f, 0.0f};
            v2f acc2 = (v2f){0.0f, 0.0f};
            v2f acc3 = (v2f){0.0f, 0.0f};
            #pragma unroll
            for (int q = 0; q < 16; q += 2) {
                float4 ha = rowp[q];
                float4 hb = rowp[q + 1];
                acc0 = __builtin_elementwise_fma(W2[2*q+0], (v2f){ha.x, ha.y}, acc0);
                acc1 = __builtin_elementwise_fma(W2[2*q+1], (v2f){ha.z, ha.w}, acc1);
                acc2 = __builtin_elementwise_fma(W2[2*q+2], (v2f){hb.x, hb.y}, acc2);
                acc3 = __builtin_elementwise_fma(W2[2*q+3], (v2f){hb.z, hb.w}, acc3);
            }
            v2f accA = acc0 + acc1;
            v2f accB = acc2 + acc3;
            v2f accT = accA + accB;
            h = tanh_fast(accT.x + accT.y);
        }

        // fc head for the chunk: lane processes row `lane` (64 rows)
        // In-wave DS ordering makes the writes above visible; keep it simple.
        {
            const float4* rp = (const float4*)(hbuf + lane * ROWSTRIDE);
            float d0 = 0.f, d1 = 0.f;
            #pragma unroll
            for (int q = 0; q < 16; ++q) {
                float4 hh = rp[q];
                float4 f0 = ((const float4*)fc_w)[q];          // uniform -> s_load
                float4 f1 = ((const float4*)(fc_w + HID))[q];
                d0 += hh.x * f0.x + hh.y * f0.y + hh.z * f0.z + hh.w * f0.w;
                d1 += hh.x * f1.x + hh.y * f1.y + hh.z * f1.z + hh.w * f1.w;
            }
            float sel = sigmoid_fast(d0 + fcb0);
            float sco = sigmoid_fast(d1 + fcb1);
            num = fmaf(sco, sel, num);
            den += sel;
        }
        // next chunk overwrites hbuf; single wave + in-order DS -> no barrier needed
    }

    // Final cross-lane reduction of (num, den)
    #pragma unroll
    for (int off = 32; off > 0; off >>= 1) {
        num += __shfl_down(num, off);
        den += __shfl_down(den, off);
    }
    if (lane == 0) out[b] = num / den;
}

extern "C" void kernel_launch(void* const* d_in, const int* in_sizes, int n_in,
                              void* d_out, int out_size, void* d_ws, size_t ws_size,
                              hipStream_t stream) {
    const float* x    = (const float*)d_in[0];
    const float* W_ih = (const float*)d_in[1];
    const float* b_ih = (const float*)d_in[2];
    const float* W_hh = (const float*)d_in[3];
    const float* b_hh = (const float*)d_in[4];
    const float* fc_w = (const float*)d_in[5];
    const float* fc_b = (const float*)d_in[6];
    float* out = (float*)d_out;

    rnn_pk_kernel<<<BATCH, 64, 0, stream>>>(x, W_ih, b_ih, W_hh, b_hh,
                                            fc_w, fc_b, out);
}